// Round 1
// baseline (1024.249 us; speedup 1.0000x reference)
//
#include <hip/hip_runtime.h>
#include <hip/hip_bf16.h>
#include <hip/hip_fp16.h>

typedef _Float16 half_t;
typedef _Float16 half8 __attribute__((ext_vector_type(8)));
typedef float f32x4 __attribute__((ext_vector_type(4)));

#define BB 8
#define SS 4096
#define DD 256
#define HH 8
#define HDIM 32
#define LL 4
#define MTOT (BB*SS)   // 32768

// ---------------- fp32 -> fp16 convert ----------------
__global__ __launch_bounds__(256) void cvt_f32_f16(const float* __restrict__ in,
                                                   half_t* __restrict__ out, int n) {
    int i = blockIdx.x * 256 + threadIdx.x;
    if (i < n) out[i] = (half_t)in[i];
}

// ---------------- LayerNorm: fp32 in -> fp16 out ----------------
__global__ __launch_bounds__(256) void ln_kernel(const float* __restrict__ in,
                                                 half_t* __restrict__ out,
                                                 const float* __restrict__ gamma,
                                                 const float* __restrict__ beta) {
    int row = blockIdx.x;
    int d = threadIdx.x;
    float x = in[(size_t)row * DD + d];
    float s1 = x, s2 = x * x;
    #pragma unroll
    for (int m = 32; m; m >>= 1) {
        s1 += __shfl_xor(s1, m);
        s2 += __shfl_xor(s2, m);
    }
    __shared__ float ls1[4], ls2[4];
    int wave = threadIdx.x >> 6, lane = threadIdx.x & 63;
    if (lane == 0) { ls1[wave] = s1; ls2[wave] = s2; }
    __syncthreads();
    float t1 = ls1[0] + ls1[1] + ls1[2] + ls1[3];
    float t2 = ls2[0] + ls2[1] + ls2[2] + ls2[3];
    float mu = t1 * (1.0f / DD);
    float var = t2 * (1.0f / DD) - mu * mu;
    float rs = rsqrtf(var + 1e-5f);
    out[(size_t)row * DD + d] = (half_t)((x - mu) * rs * gamma[d] + beta[d]);
}

// ---------------- GEMM: C[M,256] = A[M,256] @ W[256,256]^T (+epilogue) ----------------
// grid.x = M/64, block = 256 (4 waves); wave w computes rows [bid*64+w*16, +16) x all 256 cols
enum { EPI_NONE = 0, EPI_BIAS_GELU = 1, EPI_BIAS_GELU_RESID = 2 };

template<int EPI>
__global__ __launch_bounds__(256) void gemm_kernel(const half_t* __restrict__ A,
                                                   const half_t* __restrict__ W,
                                                   const float* __restrict__ bias,
                                                   const float* __restrict__ resid,
                                                   void* __restrict__ out) {
    int wave = threadIdx.x >> 6, lane = threadIdx.x & 63;
    int r = lane & 15;     // A row within tile / W row (=col) within n-tile
    int g = lane >> 4;     // k-group (8 contiguous k each)
    int row0 = blockIdx.x * 64 + wave * 16;
    const half_t* Ap = A + (size_t)(row0 + r) * DD + g * 8;
    const half_t* Wp = W + (size_t)r * DD + g * 8;
    f32x4 acc[16];
    #pragma unroll
    for (int i = 0; i < 16; ++i) acc[i] = (f32x4){0.f, 0.f, 0.f, 0.f};
    for (int k0 = 0; k0 < DD; k0 += 32) {
        half8 a = *(const half8*)(Ap + k0);
        #pragma unroll
        for (int nt = 0; nt < 16; ++nt) {
            half8 b = *(const half8*)(Wp + (size_t)nt * 16 * DD + k0);
            acc[nt] = __builtin_amdgcn_mfma_f32_16x16x32_f16(a, b, acc[nt], 0, 0, 0);
        }
    }
    // C/D layout: col = lane&15, row = (lane>>4)*4 + j
    #pragma unroll
    for (int nt = 0; nt < 16; ++nt) {
        int col = nt * 16 + r;
        #pragma unroll
        for (int j = 0; j < 4; ++j) {
            int row = row0 + g * 4 + j;
            float v = acc[nt][j];
            if (EPI != EPI_NONE) {
                v += bias[col];
                v = 0.5f * v * (1.0f + erff(v * 0.70710678118f));
            }
            if (EPI == EPI_BIAS_GELU_RESID) {
                ((float*)out)[(size_t)row * DD + col] = v + resid[(size_t)row * DD + col];
            } else {
                ((half_t*)out)[(size_t)row * DD + col] = (half_t)v;
            }
        }
    }
}

// ---------------- diag[b,h,s] = (1/64) * sum_e Q[b,s,h*32+e] * K[b, e*128+(s>>5), h*32+(s&31)]
__global__ __launch_bounds__(256) void diag_kernel(const half_t* __restrict__ Q,
                                                   const half_t* __restrict__ K,
                                                   float* __restrict__ diag) {
    int idx = blockIdx.x * 256 + threadIdx.x;   // (b,h,s), s fastest
    int s = idx & (SS - 1);
    int h = (idx >> 12) & (HH - 1);
    int b = idx >> 15;
    const half8* q8 = (const half8*)(Q + ((size_t)b * SS + s) * DD + h * HDIM);
    int c = s & 31, r0 = s >> 5;
    const half_t* kp = K + ((size_t)b * SS + r0) * DD + h * HDIM + c;
    float sum = 0.f;
    #pragma unroll
    for (int v = 0; v < 4; ++v) {
        half8 qq = q8[v];
        #pragma unroll
        for (int j = 0; j < 8; ++j) {
            int e = v * 8 + j;
            sum += (float)qq[j] * (float)kp[(size_t)e * 128 * DD];
        }
    }
    diag[idx] = sum * 0.015625f;   // 1/sqrt(4096)
}

// ---------------- attended = resid + diag*V (fp32, written); h_out = LN(attended) fp16 ----------------
__global__ __launch_bounds__(256) void attn_ln_kernel(const float* __restrict__ resid,
                                                      const half_t* __restrict__ V,
                                                      const float* __restrict__ diag,
                                                      float* __restrict__ attended,
                                                      half_t* __restrict__ hout,
                                                      const float* __restrict__ gamma,
                                                      const float* __restrict__ beta) {
    int row = blockIdx.x;          // b*S + s
    int b = row >> 12, s = row & (SS - 1);
    int d = threadIdx.x;
    float dg = diag[((size_t)b << 15) + ((size_t)(d >> 5) << 12) + s];
    float a = resid[(size_t)row * DD + d] + dg * (float)V[(size_t)row * DD + d];
    attended[(size_t)row * DD + d] = a;
    float s1 = a, s2 = a * a;
    #pragma unroll
    for (int m = 32; m; m >>= 1) {
        s1 += __shfl_xor(s1, m);
        s2 += __shfl_xor(s2, m);
    }
    __shared__ float ls1[4], ls2[4];
    int wave = threadIdx.x >> 6, lane = threadIdx.x & 63;
    if (lane == 0) { ls1[wave] = s1; ls2[wave] = s2; }
    __syncthreads();
    float t1 = ls1[0] + ls1[1] + ls1[2] + ls1[3];
    float t2 = ls2[0] + ls2[1] + ls2[2] + ls2[3];
    float mu = t1 * (1.0f / DD);
    float var = t2 * (1.0f / DD) - mu * mu;
    float rs = rsqrtf(var + 1e-5f);
    hout[(size_t)row * DD + d] = (half_t)((a - mu) * rs * gamma[d] + beta[d]);
}

// ---------------- final: LN of token 0 per batch -> fp32 out ----------------
__global__ __launch_bounds__(256) void final_ln_kernel(const float* __restrict__ cur,
                                                       float* __restrict__ out,
                                                       const float* __restrict__ gamma,
                                                       const float* __restrict__ beta) {
    int b = blockIdx.x;
    int d = threadIdx.x;
    float x = cur[(size_t)b * SS * DD + d];   // s = 0 row
    float s1 = x, s2 = x * x;
    #pragma unroll
    for (int m = 32; m; m >>= 1) {
        s1 += __shfl_xor(s1, m);
        s2 += __shfl_xor(s2, m);
    }
    __shared__ float ls1[4], ls2[4];
    int wave = threadIdx.x >> 6, lane = threadIdx.x & 63;
    if (lane == 0) { ls1[wave] = s1; ls2[wave] = s2; }
    __syncthreads();
    float t1 = ls1[0] + ls1[1] + ls1[2] + ls1[3];
    float t2 = ls2[0] + ls2[1] + ls2[2] + ls2[3];
    float mu = t1 * (1.0f / DD);
    float var = t2 * (1.0f / DD) - mu * mu;
    float rs = rsqrtf(var + 1e-5f);
    out[(size_t)b * DD + d] = (x - mu) * rs * gamma[d] + beta[d];
}

extern "C" void kernel_launch(void* const* d_in, const int* in_sizes, int n_in,
                              void* d_out, int out_size, void* d_ws, size_t ws_size,
                              hipStream_t stream) {
    const float* x     = (const float*)d_in[0];
    const float* Wq    = (const float*)d_in[1];
    const float* Wk    = (const float*)d_in[2];
    const float* Wv    = (const float*)d_in[3];
    const float* W1    = (const float*)d_in[4];
    const float* b1    = (const float*)d_in[5];
    const float* W2    = (const float*)d_in[6];
    const float* b2    = (const float*)d_in[7];
    const float* gamma = (const float*)d_in[8];
    const float* beta  = (const float*)d_in[9];

    char* p = (char*)d_ws;
    float*  cur  = (float*)p;  p += (size_t)MTOT * DD * 4;
    half_t* hbuf = (half_t*)p; p += (size_t)MTOT * DD * 2;
    half_t* Qb   = (half_t*)p; p += (size_t)MTOT * DD * 2;
    half_t* Kb   = (half_t*)p; p += (size_t)MTOT * DD * 2;
    half_t* Vb   = (half_t*)p; p += (size_t)MTOT * DD * 2;
    half_t* m1   = (half_t*)p; p += (size_t)MTOT * DD * 2;
    float*  dg   = (float*)p;  p += (size_t)BB * HH * SS * 4;
    half_t* Wqh  = (half_t*)p; p += (size_t)LL * 65536 * 2;
    half_t* Wkh  = (half_t*)p; p += (size_t)LL * 65536 * 2;
    half_t* Wvh  = (half_t*)p; p += (size_t)LL * 65536 * 2;
    half_t* W1h  = (half_t*)p; p += (size_t)LL * 65536 * 2;
    half_t* W2h  = (half_t*)p; p += (size_t)LL * 65536 * 2;

    const int NW = LL * 65536;   // 262144 elems per weight tensor
    cvt_f32_f16<<<NW / 256, 256, 0, stream>>>(Wq, Wqh, NW);
    cvt_f32_f16<<<NW / 256, 256, 0, stream>>>(Wk, Wkh, NW);
    cvt_f32_f16<<<NW / 256, 256, 0, stream>>>(Wv, Wvh, NW);
    cvt_f32_f16<<<NW / 256, 256, 0, stream>>>(W1, W1h, NW);
    cvt_f32_f16<<<NW / 256, 256, 0, stream>>>(W2, W2h, NW);

    const float* curin = x;
    for (int l = 0; l < LL; ++l) {
        ln_kernel<<<MTOT, 256, 0, stream>>>(curin, hbuf, gamma, beta);
        gemm_kernel<EPI_NONE><<<MTOT / 64, 256, 0, stream>>>(hbuf, Wqh + (size_t)l * 65536, nullptr, nullptr, Qb);
        gemm_kernel<EPI_NONE><<<MTOT / 64, 256, 0, stream>>>(hbuf, Wkh + (size_t)l * 65536, nullptr, nullptr, Kb);
        gemm_kernel<EPI_NONE><<<MTOT / 64, 256, 0, stream>>>(hbuf, Wvh + (size_t)l * 65536, nullptr, nullptr, Vb);
        diag_kernel<<<(BB * HH * SS) / 256, 256, 0, stream>>>(Qb, Kb, dg);
        attn_ln_kernel<<<MTOT, 256, 0, stream>>>(curin, Vb, dg, cur, hbuf, gamma, beta);
        gemm_kernel<EPI_BIAS_GELU><<<MTOT / 64, 256, 0, stream>>>(hbuf, W1h + (size_t)l * 65536, b1 + l * 256, nullptr, m1);
        gemm_kernel<EPI_BIAS_GELU_RESID><<<MTOT / 64, 256, 0, stream>>>(m1, W2h + (size_t)l * 65536, b2 + l * 256, cur, cur);
        curin = cur;
    }
    final_ln_kernel<<<BB, 256, 0, stream>>>(cur, (float*)d_out, gamma, beta);
}

// Round 2
// 773.911 us; speedup vs baseline: 1.3235x; 1.3235x over previous
//
#include <hip/hip_runtime.h>
#include <hip/hip_bf16.h>
#include <hip/hip_fp16.h>

typedef _Float16 half_t;
typedef _Float16 half8 __attribute__((ext_vector_type(8)));
typedef float f32x4 __attribute__((ext_vector_type(4)));

#define BB 8
#define SS 4096
#define DD 256
#define HH 8
#define HDIM 32
#define LL 4
#define MTOT (BB*SS)   // 32768

// ---------------- fp32 -> fp16 weight convert (all 5 weight tensors, one launch) ----------
// Wq/Wk/Wv go to a combined buffer: Wall[(l*3 + which)*65536 + (row*256+col)]
__global__ __launch_bounds__(256) void cvt_all(const float* __restrict__ Wq, const float* __restrict__ Wk,
                                               const float* __restrict__ Wv, const float* __restrict__ W1,
                                               const float* __restrict__ W2,
                                               half_t* __restrict__ Wall, half_t* __restrict__ W1h,
                                               half_t* __restrict__ W2h) {
    int i = blockIdx.x * 256 + threadIdx.x;      // 0 .. 5*262144
    int w = i >> 18;
    int j = i & 262143;
    const float* src = (w == 0) ? Wq : (w == 1) ? Wk : (w == 2) ? Wv : (w == 3) ? W1 : W2;
    float v = src[j];
    if (w < 3) {
        int l = j >> 16, k = j & 65535;
        Wall[((size_t)l * 3 + w) * 65536 + k] = (half_t)v;
    } else if (w == 3) W1h[j] = (half_t)v;
    else W2h[j] = (half_t)v;
}

// ---------------- LayerNorm: fp32 in -> fp16 out ----------------
__global__ __launch_bounds__(256) void ln_kernel(const float* __restrict__ in,
                                                 half_t* __restrict__ out,
                                                 const float* __restrict__ gamma,
                                                 const float* __restrict__ beta) {
    int row = blockIdx.x;
    int d = threadIdx.x;
    float x = in[(size_t)row * DD + d];
    float s1 = x, s2 = x * x;
    #pragma unroll
    for (int m = 32; m; m >>= 1) {
        s1 += __shfl_xor(s1, m);
        s2 += __shfl_xor(s2, m);
    }
    __shared__ float ls1[4], ls2[4];
    int wave = threadIdx.x >> 6, lane = threadIdx.x & 63;
    if (lane == 0) { ls1[wave] = s1; ls2[wave] = s2; }
    __syncthreads();
    float t1 = ls1[0] + ls1[1] + ls1[2] + ls1[3];
    float t2 = ls2[0] + ls2[1] + ls2[2] + ls2[3];
    float mu = t1 * (1.0f / DD);
    float var = t2 * (1.0f / DD) - mu * mu;
    float rs = rsqrtf(var + 1e-5f);
    out[(size_t)row * DD + d] = (half_t)((x - mu) * rs * gamma[d] + beta[d]);
}

// ---------------- Tiled GEMM: C[M,256] = A[M,256] @ W[256,256]^T (+epilogue) ----------------
// BM=BN=128, BK=64. 256 threads = 4 waves, wave tile 64x64 (4x4 16x16x32 mfma frags).
// LDS: A,B tiles 16KB each, single-buffered, XOR-swizzled (chunk ^= row&7 on 16B granules).
// grid = (M/128, N/128=2, nz); z selects weight (QKV fusion) and output pointer.
enum { EPI_NONE = 0, EPI_BIAS_GELU = 1, EPI_BIAS_GELU_RESID = 2 };

template<int EPI>
__global__ __launch_bounds__(256) void gemm2(const half_t* __restrict__ A,
                                             const half_t* __restrict__ Wbase,
                                             const float* __restrict__ bias,
                                             const float* __restrict__ resid,
                                             half_t* __restrict__ o0,
                                             half_t* __restrict__ o1,
                                             half_t* __restrict__ o2,
                                             float* __restrict__ outf) {
    const int t = threadIdx.x;
    const int lane = t & 63;
    const int wave = t >> 6;
    const int wm = wave >> 1, wn = wave & 1;
    const int r = lane & 15, g = lane >> 4;
    const int row0 = blockIdx.x * 128;
    const int col0 = blockIdx.y * 128;
    const int z = blockIdx.z;
    const half_t* W = Wbase + (size_t)z * 65536;
    half_t* oh = (z == 0) ? o0 : ((z == 1) ? o1 : o2);

    __shared__ __align__(16) half_t ldsA[128 * 64];
    __shared__ __align__(16) half_t ldsB[128 * 64];

    f32x4 acc[4][4];
    #pragma unroll
    for (int i = 0; i < 4; ++i)
        #pragma unroll
        for (int j2 = 0; j2 < 4; ++j2) acc[i][j2] = (f32x4){0.f, 0.f, 0.f, 0.f};

    const half_t* Ag = A + (size_t)row0 * DD;
    const half_t* Wg = W + (size_t)col0 * DD;

    // staging granule map: granule G (16B): LDS row = G>>3, LDS chunk = G&7,
    // source global chunk = (G&7) ^ (row&7)   [swizzle involution]
    int rwi[4], ci[4];
    #pragma unroll
    for (int i = 0; i < 4; ++i) {
        int G = i * 256 + t;
        rwi[i] = G >> 3;
        ci[i] = (G & 7) ^ ((G >> 3) & 7);
    }

    int4 ra[4], rb[4];
    #pragma unroll
    for (int i = 0; i < 4; ++i) {
        ra[i] = *(const int4*)(Ag + (size_t)rwi[i] * DD + ci[i] * 8);
        rb[i] = *(const int4*)(Wg + (size_t)rwi[i] * DD + ci[i] * 8);
    }
    #pragma unroll
    for (int i = 0; i < 4; ++i) {
        *(int4*)&ldsA[(i * 256 + t) * 8] = ra[i];
        *(int4*)&ldsB[(i * 256 + t) * 8] = rb[i];
    }
    __syncthreads();

    #pragma unroll
    for (int stp = 0; stp < 4; ++stp) {
        if (stp < 3) {                            // T14: issue next-step loads early
            int kk = (stp + 1) * 64;
            #pragma unroll
            for (int i = 0; i < 4; ++i) {
                ra[i] = *(const int4*)(Ag + (size_t)rwi[i] * DD + kk + ci[i] * 8);
                rb[i] = *(const int4*)(Wg + (size_t)rwi[i] * DD + kk + ci[i] * 8);
            }
        }
        #pragma unroll
        for (int ks = 0; ks < 2; ++ks) {
            half8 af[4], bf[4];
            #pragma unroll
            for (int mt = 0; mt < 4; ++mt) {
                int rw = wm * 64 + mt * 16 + r;
                int cc = (g + ks * 4) ^ (rw & 7);
                af[mt] = *(const half8*)&ldsA[rw * 64 + cc * 8];
            }
            #pragma unroll
            for (int nt = 0; nt < 4; ++nt) {
                int rw = wn * 64 + nt * 16 + r;
                int cc = (g + ks * 4) ^ (rw & 7);
                bf[nt] = *(const half8*)&ldsB[rw * 64 + cc * 8];
            }
            #pragma unroll
            for (int mt = 0; mt < 4; ++mt)
                #pragma unroll
                for (int nt = 0; nt < 4; ++nt)
                    acc[mt][nt] = __builtin_amdgcn_mfma_f32_16x16x32_f16(af[mt], bf[nt], acc[mt][nt], 0, 0, 0);
        }
        __syncthreads();
        if (stp < 3) {
            #pragma unroll
            for (int i = 0; i < 4; ++i) {
                *(int4*)&ldsA[(i * 256 + t) * 8] = ra[i];
                *(int4*)&ldsB[(i * 256 + t) * 8] = rb[i];
            }
            __syncthreads();
        }
    }

    // epilogue: C/D layout col = lane&15, row = (lane>>4)*4 + j
    #pragma unroll
    for (int mt = 0; mt < 4; ++mt) {
        #pragma unroll
        for (int nt = 0; nt < 4; ++nt) {
            int col = col0 + wn * 64 + nt * 16 + r;
            float bv = (EPI != EPI_NONE) ? bias[col] : 0.f;
            #pragma unroll
            for (int j = 0; j < 4; ++j) {
                int row = row0 + wm * 64 + mt * 16 + g * 4 + j;
                float v = acc[mt][nt][j];
                if (EPI != EPI_NONE) {
                    v += bv;
                    v = 0.5f * v * (1.0f + erff(v * 0.70710678118f));
                }
                if (EPI == EPI_BIAS_GELU_RESID) {
                    outf[(size_t)row * DD + col] = v + resid[(size_t)row * DD + col];
                } else {
                    oh[(size_t)row * DD + col] = (half_t)v;
                }
            }
        }
    }
}

// ---------------- diag[b,h,s] = (1/64) * sum_e Q[b,s,h*32+e] * K[b, e*128+(s>>5), h*32+(s&31)]
__global__ __launch_bounds__(256) void diag_kernel(const half_t* __restrict__ Q,
                                                   const half_t* __restrict__ K,
                                                   float* __restrict__ diag) {
    int idx = blockIdx.x * 256 + threadIdx.x;   // (b,h,s), s fastest
    int s = idx & (SS - 1);
    int h = (idx >> 12) & (HH - 1);
    int b = idx >> 15;
    const half8* q8 = (const half8*)(Q + ((size_t)b * SS + s) * DD + h * HDIM);
    int c = s & 31, r0 = s >> 5;
    const half_t* kp = K + ((size_t)b * SS + r0) * DD + h * HDIM + c;
    float sum = 0.f;
    #pragma unroll
    for (int v = 0; v < 4; ++v) {
        half8 qq = q8[v];
        #pragma unroll
        for (int j = 0; j < 8; ++j) {
            int e = v * 8 + j;
            sum += (float)qq[j] * (float)kp[(size_t)e * 128 * DD];
        }
    }
    diag[idx] = sum * 0.015625f;   // 1/sqrt(4096)
}

// ---------------- attended = resid + diag*V (fp32, written); h_out = LN(attended) fp16 ----------------
__global__ __launch_bounds__(256) void attn_ln_kernel(const float* __restrict__ resid,
                                                      const half_t* __restrict__ V,
                                                      const float* __restrict__ diag,
                                                      float* __restrict__ attended,
                                                      half_t* __restrict__ hout,
                                                      const float* __restrict__ gamma,
                                                      const float* __restrict__ beta) {
    int row = blockIdx.x;          // b*S + s
    int b = row >> 12, s = row & (SS - 1);
    int d = threadIdx.x;
    float dg = diag[((size_t)b << 15) + ((size_t)(d >> 5) << 12) + s];
    float a = resid[(size_t)row * DD + d] + dg * (float)V[(size_t)row * DD + d];
    attended[(size_t)row * DD + d] = a;
    float s1 = a, s2 = a * a;
    #pragma unroll
    for (int m = 32; m; m >>= 1) {
        s1 += __shfl_xor(s1, m);
        s2 += __shfl_xor(s2, m);
    }
    __shared__ float ls1[4], ls2[4];
    int wave = threadIdx.x >> 6, lane = threadIdx.x & 63;
    if (lane == 0) { ls1[wave] = s1; ls2[wave] = s2; }
    __syncthreads();
    float t1 = ls1[0] + ls1[1] + ls1[2] + ls1[3];
    float t2 = ls2[0] + ls2[1] + ls2[2] + ls2[3];
    float mu = t1 * (1.0f / DD);
    float var = t2 * (1.0f / DD) - mu * mu;
    float rs = rsqrtf(var + 1e-5f);
    hout[(size_t)row * DD + d] = (half_t)((a - mu) * rs * gamma[d] + beta[d]);
}

// ---------------- final: LN of token 0 per batch -> fp32 out ----------------
__global__ __launch_bounds__(256) void final_ln_kernel(const float* __restrict__ cur,
                                                       float* __restrict__ out,
                                                       const float* __restrict__ gamma,
                                                       const float* __restrict__ beta) {
    int b = blockIdx.x;
    int d = threadIdx.x;
    float x = cur[(size_t)b * SS * DD + d];   // s = 0 row
    float s1 = x, s2 = x * x;
    #pragma unroll
    for (int m = 32; m; m >>= 1) {
        s1 += __shfl_xor(s1, m);
        s2 += __shfl_xor(s2, m);
    }
    __shared__ float ls1[4], ls2[4];
    int wave = threadIdx.x >> 6, lane = threadIdx.x & 63;
    if (lane == 0) { ls1[wave] = s1; ls2[wave] = s2; }
    __syncthreads();
    float t1 = ls1[0] + ls1[1] + ls1[2] + ls1[3];
    float t2 = ls2[0] + ls2[1] + ls2[2] + ls2[3];
    float mu = t1 * (1.0f / DD);
    float var = t2 * (1.0f / DD) - mu * mu;
    float rs = rsqrtf(var + 1e-5f);
    out[(size_t)b * DD + d] = (x - mu) * rs * gamma[d] + beta[d];
}

extern "C" void kernel_launch(void* const* d_in, const int* in_sizes, int n_in,
                              void* d_out, int out_size, void* d_ws, size_t ws_size,
                              hipStream_t stream) {
    const float* x     = (const float*)d_in[0];
    const float* Wq    = (const float*)d_in[1];
    const float* Wk    = (const float*)d_in[2];
    const float* Wv    = (const float*)d_in[3];
    const float* W1    = (const float*)d_in[4];
    const float* b1    = (const float*)d_in[5];
    const float* W2    = (const float*)d_in[6];
    const float* b2    = (const float*)d_in[7];
    const float* gamma = (const float*)d_in[8];
    const float* beta  = (const float*)d_in[9];

    char* p = (char*)d_ws;
    float*  cur  = (float*)p;  p += (size_t)MTOT * DD * 4;
    half_t* hbuf = (half_t*)p; p += (size_t)MTOT * DD * 2;
    half_t* Qb   = (half_t*)p; p += (size_t)MTOT * DD * 2;
    half_t* Kb   = (half_t*)p; p += (size_t)MTOT * DD * 2;
    half_t* Vb   = (half_t*)p; p += (size_t)MTOT * DD * 2;
    half_t* m1   = (half_t*)p; p += (size_t)MTOT * DD * 2;
    float*  dg   = (float*)p;  p += (size_t)BB * HH * SS * 4;
    half_t* Wall = (half_t*)p; p += (size_t)LL * 3 * 65536 * 2;
    half_t* W1h  = (half_t*)p; p += (size_t)LL * 65536 * 2;
    half_t* W2h  = (half_t*)p; p += (size_t)LL * 65536 * 2;

    cvt_all<<<5120, 256, 0, stream>>>(Wq, Wk, Wv, W1, W2, Wall, W1h, W2h);

    const float* curin = x;
    for (int l = 0; l < LL; ++l) {
        ln_kernel<<<MTOT, 256, 0, stream>>>(curin, hbuf, gamma, beta);
        gemm2<EPI_NONE><<<dim3(256, 2, 3), 256, 0, stream>>>(
            hbuf, Wall + (size_t)l * 3 * 65536, nullptr, nullptr, Qb, Kb, Vb, nullptr);
        diag_kernel<<<(BB * HH * SS) / 256, 256, 0, stream>>>(Qb, Kb, dg);
        attn_ln_kernel<<<MTOT, 256, 0, stream>>>(curin, Vb, dg, cur, hbuf, gamma, beta);
        gemm2<EPI_BIAS_GELU><<<dim3(256, 2, 1), 256, 0, stream>>>(
            hbuf, W1h + (size_t)l * 65536, b1 + l * 256, nullptr, m1, m1, m1, nullptr);
        gemm2<EPI_BIAS_GELU_RESID><<<dim3(256, 2, 1), 256, 0, stream>>>(
            m1, W2h + (size_t)l * 65536, b2 + l * 256, cur, nullptr, nullptr, nullptr, cur);
        curin = cur;
    }
    final_ln_kernel<<<BB, 256, 0, stream>>>(cur, (float*)d_out, gamma, beta);
}

// Round 3
// 579.750 us; speedup vs baseline: 1.7667x; 1.3349x over previous
//
#include <hip/hip_runtime.h>
#include <hip/hip_bf16.h>
#include <hip/hip_fp16.h>

typedef _Float16 half_t;
typedef _Float16 half8 __attribute__((ext_vector_type(8)));
typedef _Float16 half4 __attribute__((ext_vector_type(4)));
typedef float f32x4 __attribute__((ext_vector_type(4)));

#define BB 8
#define SS 4096
#define DD 256
#define HH 8
#define LL 4
#define MTOT (BB*SS)   // 32768

// ---------------- weight fp32 -> fp16 (Wq/Wk/Wv combined per layer) ----------------
__global__ __launch_bounds__(256) void cvt_all(const float* __restrict__ Wq, const float* __restrict__ Wk,
                                               const float* __restrict__ Wv, const float* __restrict__ W1,
                                               const float* __restrict__ W2,
                                               half_t* __restrict__ Wall, half_t* __restrict__ W1h,
                                               half_t* __restrict__ W2h) {
    int i = blockIdx.x * 256 + threadIdx.x;      // 0 .. 5*262144
    int w = i >> 18;
    int j = i & 262143;
    const float* src = (w == 0) ? Wq : (w == 1) ? Wk : (w == 2) ? Wv : (w == 3) ? W1 : W2;
    float v = src[j];
    if (w < 3) {
        int l = j >> 16, k = j & 65535;
        Wall[((size_t)l * 3 + w) * 65536 + k] = (half_t)v;
    } else if (w == 3) W1h[j] = (half_t)v;
    else W2h[j] = (half_t)v;
}

// ---------------- x fp32 -> fp16 ----------------
__global__ __launch_bounds__(256) void cvt_x(const float* __restrict__ in, half_t* __restrict__ out) {
    int i = (blockIdx.x * 256 + threadIdx.x) * 4;
    float4 v = *(const float4*)(in + i);
    half4 h = { (half_t)v.x, (half_t)v.y, (half_t)v.z, (half_t)v.w };
    *(half4*)(out + i) = h;
}

// ---------------- LayerNorm fp16 -> fp16, one wave per row ----------------
__global__ __launch_bounds__(256) void ln16(const half_t* __restrict__ in,
                                            half_t* __restrict__ out,
                                            const float* __restrict__ gamma,
                                            const float* __restrict__ beta) {
    int wave = threadIdx.x >> 6, lane = threadIdx.x & 63;
    int row = blockIdx.x * 4 + wave;
    size_t base = (size_t)row * DD + lane * 4;
    half4 x4 = *(const half4*)(in + base);
    float x0 = x4[0], x1 = x4[1], x2 = x4[2], x3 = x4[3];
    float s1 = x0 + x1 + x2 + x3;
    float s2 = x0 * x0 + x1 * x1 + x2 * x2 + x3 * x3;
    #pragma unroll
    for (int m = 32; m; m >>= 1) {
        s1 += __shfl_xor(s1, m);
        s2 += __shfl_xor(s2, m);
    }
    float mu = s1 * (1.0f / DD);
    float var = s2 * (1.0f / DD) - mu * mu;
    float rs = rsqrtf(var + 1e-5f);
    float4 g4 = *(const float4*)(gamma + lane * 4);
    float4 b4 = *(const float4*)(beta + lane * 4);
    half4 o = { (half_t)((x0 - mu) * rs * g4.x + b4.x), (half_t)((x1 - mu) * rs * g4.y + b4.y),
                (half_t)((x2 - mu) * rs * g4.z + b4.z), (half_t)((x3 - mu) * rs * g4.w + b4.w) };
    *(half4*)(out + base) = o;
}

// ---------------- XCD-aware bijective remap ----------------
__device__ inline void xcd_remap(int& bx, int& by, int& bz) {
    int lin = blockIdx.x + gridDim.x * (blockIdx.y + gridDim.y * blockIdx.z);
    int nyz = gridDim.y * gridDim.z;
    int xcd = lin & 7;
    int slot = lin >> 3;
    int yz = slot % nyz;
    int xi = slot / nyz;
    bx = xcd + 8 * xi;          // gridDim.x must be divisible by 8
    by = yz % gridDim.y;
    bz = yz / gridDim.y;
}

// ---------------- Tiled GEMM: C[M,256] = A[M,256] @ W[256,256]^T (+epilogue) ----------------
// BM=BN=128, BK=64, 4 waves (2x2), 4x4 16x16x32 frags per wave. fp16 out, coalesced
// epilogue via LDS transpose. grid.z selects weight/output (QKV fusion).
enum { EPI_NONE = 0, EPI_BIAS_GELU = 1, EPI_BIAS_GELU_RESID = 2 };

template<int EPI>
__global__ __launch_bounds__(256) void gemm2(const half_t* __restrict__ A,
                                             const half_t* __restrict__ Wbase,
                                             const float* __restrict__ bias,
                                             const half_t* __restrict__ resid,
                                             half_t* __restrict__ o0,
                                             half_t* __restrict__ o1,
                                             half_t* __restrict__ o2) {
    const int t = threadIdx.x;
    const int lane = t & 63;
    const int wave = t >> 6;
    const int wm = wave >> 1, wn = wave & 1;
    const int r = lane & 15, g = lane >> 4;
    int bx, by, bz;
    xcd_remap(bx, by, bz);
    const int row0 = bx * 128;
    const int col0 = by * 128;
    const half_t* W = Wbase + (size_t)bz * 65536;
    half_t* outp = (bz == 0) ? o0 : ((bz == 1) ? o1 : o2);

    __shared__ __align__(16) half_t lds[128 * 128];   // A: [0,8K), B: [8K,16K) halfs
    half_t* ldsA = lds;
    half_t* ldsB = lds + 128 * 64;

    f32x4 acc[4][4];
    #pragma unroll
    for (int i = 0; i < 4; ++i)
        #pragma unroll
        for (int j2 = 0; j2 < 4; ++j2) acc[i][j2] = (f32x4){0.f, 0.f, 0.f, 0.f};

    const half_t* Ag = A + (size_t)row0 * DD;
    const half_t* Wg = W + (size_t)col0 * DD;

    // staging: granule G (16B): LDS row G>>3, chunk G&7; global chunk = (G&7)^(row&7)
    int rwi[4], ci[4];
    #pragma unroll
    for (int i = 0; i < 4; ++i) {
        int G = i * 256 + t;
        rwi[i] = G >> 3;
        ci[i] = (G & 7) ^ ((G >> 3) & 7);
    }

    int4 ra[4], rb[4];
    #pragma unroll
    for (int i = 0; i < 4; ++i) {
        ra[i] = *(const int4*)(Ag + (size_t)rwi[i] * DD + ci[i] * 8);
        rb[i] = *(const int4*)(Wg + (size_t)rwi[i] * DD + ci[i] * 8);
    }
    #pragma unroll
    for (int i = 0; i < 4; ++i) {
        *(int4*)&ldsA[(i * 256 + t) * 8] = ra[i];
        *(int4*)&ldsB[(i * 256 + t) * 8] = rb[i];
    }
    __syncthreads();

    #pragma unroll
    for (int stp = 0; stp < 4; ++stp) {
        if (stp < 3) {                            // issue next-step loads early (T14)
            int kk = (stp + 1) * 64;
            #pragma unroll
            for (int i = 0; i < 4; ++i) {
                ra[i] = *(const int4*)(Ag + (size_t)rwi[i] * DD + kk + ci[i] * 8);
                rb[i] = *(const int4*)(Wg + (size_t)rwi[i] * DD + kk + ci[i] * 8);
            }
        }
        #pragma unroll
        for (int ks = 0; ks < 2; ++ks) {
            half8 af[4], bf[4];
            #pragma unroll
            for (int mt = 0; mt < 4; ++mt) {
                int rw = wm * 64 + mt * 16 + r;
                int cc = (g + ks * 4) ^ (rw & 7);
                af[mt] = *(const half8*)&ldsA[rw * 64 + cc * 8];
            }
            #pragma unroll
            for (int nt = 0; nt < 4; ++nt) {
                int rw = wn * 64 + nt * 16 + r;
                int cc = (g + ks * 4) ^ (rw & 7);
                bf[nt] = *(const half8*)&ldsB[rw * 64 + cc * 8];
            }
            #pragma unroll
            for (int mt = 0; mt < 4; ++mt)
                #pragma unroll
                for (int nt = 0; nt < 4; ++nt)
                    acc[mt][nt] = __builtin_amdgcn_mfma_f32_16x16x32_f16(af[mt], bf[nt], acc[mt][nt], 0, 0, 0);
        }
        __syncthreads();
        if (stp < 3) {
            #pragma unroll
            for (int i = 0; i < 4; ++i) {
                *(int4*)&ldsA[(i * 256 + t) * 8] = ra[i];
                *(int4*)&ldsB[(i * 256 + t) * 8] = rb[i];
            }
            __syncthreads();
        }
    }

    // ---- epilogue: acc -> LDS (swizzled fp16) -> coalesced half8 stores ----
    // C/D frag layout: col = lane&15 (r), row = (lane>>4)*4 + j (g,j)
    #pragma unroll
    for (int mt = 0; mt < 4; ++mt) {
        #pragma unroll
        for (int nt = 0; nt < 4; ++nt) {
            int colL = wn * 64 + nt * 16 + r;
            float bv = (EPI != EPI_NONE) ? bias[col0 + colL] : 0.f;
            #pragma unroll
            for (int j = 0; j < 4; ++j) {
                int rowL = wm * 64 + mt * 16 + g * 4 + j;
                float v = acc[mt][nt][j];
                if (EPI != EPI_NONE) {
                    v += bv;
                    v = 0.5f * v * (1.0f + erff(v * 0.70710678118f));
                }
                lds[rowL * 128 + (colL ^ ((rowL & 12) << 2))] = (half_t)v;
            }
        }
    }
    __syncthreads();
    const int l15 = lane & 15, lg = lane >> 4;
    #pragma unroll
    for (int i = 0; i < 8; ++i) {
        int rowL = wave * 32 + lg * 8 + i;
        int colL = l15 * 8;
        half8 v = *(const half8*)&lds[rowL * 128 + (colL ^ ((rowL & 12) << 2))];
        size_t off = (size_t)(row0 + rowL) * DD + col0 + colL;
        if (EPI == EPI_BIAS_GELU_RESID) {
            half8 rsd = *(const half8*)&resid[off];
            #pragma unroll
            for (int q = 0; q < 8; ++q) v[q] = (half_t)((float)v[q] + (float)rsd[q]);
        }
        *(half8*)&outp[off] = v;
    }
}

// ---------------- diag[b,h,s] = (1/64) * sum_e Q[b,s,h*32+e] * K[b, e*128+(s>>5), h*32+(s&31)]
__global__ __launch_bounds__(256) void diag_kernel(const half_t* __restrict__ Q,
                                                   const half_t* __restrict__ K,
                                                   float* __restrict__ diag) {
    int idx = blockIdx.x * 256 + threadIdx.x;   // (b,h,s), s fastest
    int s = idx & (SS - 1);
    int h = (idx >> 12) & (HH - 1);
    int b = idx >> 15;
    const half8* q8 = (const half8*)(Q + ((size_t)b * SS + s) * DD + h * 32);
    int c = s & 31, r0 = s >> 5;
    const half_t* kp = K + ((size_t)b * SS + r0) * DD + h * 32 + c;
    float sum = 0.f;
    #pragma unroll
    for (int v = 0; v < 4; ++v) {
        half8 qq = q8[v];
        #pragma unroll
        for (int j = 0; j < 8; ++j) {
            int e = v * 8 + j;
            sum += (float)qq[j] * (float)kp[(size_t)e * 128 * DD];
        }
    }
    diag[idx] = sum * 0.015625f;   // 1/sqrt(4096)
}

// ---------------- attended = resid + diag*V (fp16); hout = LN(attended) fp16; 1 wave/row ----
__global__ __launch_bounds__(256) void attn_ln16(const half_t* __restrict__ resid,
                                                 const half_t* __restrict__ V,
                                                 const float* __restrict__ diag,
                                                 half_t* __restrict__ attended,
                                                 half_t* __restrict__ hout,
                                                 const float* __restrict__ gamma,
                                                 const float* __restrict__ beta) {
    int wave = threadIdx.x >> 6, lane = threadIdx.x & 63;
    int row = blockIdx.x * 4 + wave;           // b*S + s
    int b = row >> 12, s = row & (SS - 1);
    int h = lane >> 3;                          // head of cols [lane*4, lane*4+3]
    float dg = diag[((size_t)b << 15) + ((size_t)h << 12) + s];
    size_t base = (size_t)row * DD + lane * 4;
    half4 rs4 = *(const half4*)(resid + base);
    half4 v4 = *(const half4*)(V + base);
    float a0 = (float)rs4[0] + dg * (float)v4[0];
    float a1 = (float)rs4[1] + dg * (float)v4[1];
    float a2 = (float)rs4[2] + dg * (float)v4[2];
    float a3 = (float)rs4[3] + dg * (float)v4[3];
    half4 at = { (half_t)a0, (half_t)a1, (half_t)a2, (half_t)a3 };
    *(half4*)(attended + base) = at;
    float s1 = a0 + a1 + a2 + a3;
    float s2 = a0 * a0 + a1 * a1 + a2 * a2 + a3 * a3;
    #pragma unroll
    for (int m = 32; m; m >>= 1) {
        s1 += __shfl_xor(s1, m);
        s2 += __shfl_xor(s2, m);
    }
    float mu = s1 * (1.0f / DD);
    float var = s2 * (1.0f / DD) - mu * mu;
    float rsq = rsqrtf(var + 1e-5f);
    float4 g4 = *(const float4*)(gamma + lane * 4);
    float4 b4 = *(const float4*)(beta + lane * 4);
    half4 o = { (half_t)((a0 - mu) * rsq * g4.x + b4.x), (half_t)((a1 - mu) * rsq * g4.y + b4.y),
                (half_t)((a2 - mu) * rsq * g4.z + b4.z), (half_t)((a3 - mu) * rsq * g4.w + b4.w) };
    *(half4*)(hout + base) = o;
}

// ---------------- final: LN of token 0 per batch -> fp32 out ----------------
__global__ __launch_bounds__(256) void final_ln_kernel(const half_t* __restrict__ cur,
                                                       float* __restrict__ out,
                                                       const float* __restrict__ gamma,
                                                       const float* __restrict__ beta) {
    int b = blockIdx.x;
    int d = threadIdx.x;
    float x = (float)cur[(size_t)b * SS * DD + d];   // s = 0 row
    float s1 = x, s2 = x * x;
    #pragma unroll
    for (int m = 32; m; m >>= 1) {
        s1 += __shfl_xor(s1, m);
        s2 += __shfl_xor(s2, m);
    }
    __shared__ float ls1[4], ls2[4];
    int wave = threadIdx.x >> 6, lane = threadIdx.x & 63;
    if (lane == 0) { ls1[wave] = s1; ls2[wave] = s2; }
    __syncthreads();
    float t1 = ls1[0] + ls1[1] + ls1[2] + ls1[3];
    float t2 = ls2[0] + ls2[1] + ls2[2] + ls2[3];
    float mu = t1 * (1.0f / DD);
    float var = t2 * (1.0f / DD) - mu * mu;
    float rs = rsqrtf(var + 1e-5f);
    out[(size_t)b * DD + d] = (x - mu) * rs * gamma[d] + beta[d];
}

extern "C" void kernel_launch(void* const* d_in, const int* in_sizes, int n_in,
                              void* d_out, int out_size, void* d_ws, size_t ws_size,
                              hipStream_t stream) {
    const float* x     = (const float*)d_in[0];
    const float* Wq    = (const float*)d_in[1];
    const float* Wk    = (const float*)d_in[2];
    const float* Wv    = (const float*)d_in[3];
    const float* W1    = (const float*)d_in[4];
    const float* b1    = (const float*)d_in[5];
    const float* W2    = (const float*)d_in[6];
    const float* b2    = (const float*)d_in[7];
    const float* gamma = (const float*)d_in[8];
    const float* beta  = (const float*)d_in[9];

    char* p = (char*)d_ws;
    half_t* x16  = (half_t*)p; p += (size_t)MTOT * DD * 2;
    half_t* cur  = (half_t*)p; p += (size_t)MTOT * DD * 2;
    half_t* att  = (half_t*)p; p += (size_t)MTOT * DD * 2;
    half_t* hbuf = (half_t*)p; p += (size_t)MTOT * DD * 2;
    half_t* Qb   = (half_t*)p; p += (size_t)MTOT * DD * 2;
    half_t* Kb   = (half_t*)p; p += (size_t)MTOT * DD * 2;
    half_t* Vb   = (half_t*)p; p += (size_t)MTOT * DD * 2;
    half_t* m1   = (half_t*)p; p += (size_t)MTOT * DD * 2;
    float*  dg   = (float*)p;  p += (size_t)BB * HH * SS * 4;
    half_t* Wall = (half_t*)p; p += (size_t)LL * 3 * 65536 * 2;
    half_t* W1h  = (half_t*)p; p += (size_t)LL * 65536 * 2;
    half_t* W2h  = (half_t*)p; p += (size_t)LL * 65536 * 2;

    cvt_all<<<5120, 256, 0, stream>>>(Wq, Wk, Wv, W1, W2, Wall, W1h, W2h);
    cvt_x<<<8192, 256, 0, stream>>>(x, x16);

    const half_t* curin = x16;
    for (int l = 0; l < LL; ++l) {
        ln16<<<MTOT / 4, 256, 0, stream>>>(curin, hbuf, gamma, beta);
        gemm2<EPI_NONE><<<dim3(256, 2, 3), 256, 0, stream>>>(
            hbuf, Wall + (size_t)l * 3 * 65536, nullptr, nullptr, Qb, Kb, Vb);
        diag_kernel<<<(BB * HH * SS) / 256, 256, 0, stream>>>(Qb, Kb, dg);
        attn_ln16<<<MTOT / 4, 256, 0, stream>>>(curin, Vb, dg, att, hbuf, gamma, beta);
        gemm2<EPI_BIAS_GELU><<<dim3(256, 2, 1), 256, 0, stream>>>(
            hbuf, W1h + (size_t)l * 65536, b1 + l * 256, nullptr, m1, m1, m1);
        gemm2<EPI_BIAS_GELU_RESID><<<dim3(256, 2, 1), 256, 0, stream>>>(
            m1, W2h + (size_t)l * 65536, b2 + l * 256, att, cur, cur, cur);
        curin = cur;
    }
    final_ln_kernel<<<BB, 256, 0, stream>>>(cur, (float*)d_out, gamma, beta);
}